// Round 5
// baseline (421.472 us; speedup 1.0000x reference)
//
#include <hip/hip_runtime.h>
#include <hip/hip_bf16.h>

// GAT encoder, 2 layers, N=50000, Et=850000, IN=128, HID=OUT=256, HEADS=8, C=32.
// fp16 activations + MFMA f16 GEMM (64x256 tile, fused al epilogue, T14 load pipeline);
// softmax split out (k_alpha -> fp16 alpha in gmem), pure streaming gather (k_gather).

#define HEADS 8
#define F 256

typedef _Float16 h8 __attribute__((ext_vector_type(8)));
typedef _Float16 h4 __attribute__((ext_vector_type(4)));
typedef float f4 __attribute__((ext_vector_type(4)));

// ---------------- conversions ----------------

__global__ void k_cvt(const float* __restrict__ in, _Float16* __restrict__ out, int n) {
  int i = blockIdx.x * blockDim.x + threadIdx.x;
  int idx = i * 4;
  if (idx < n) {
    float4 v = *(const float4*)&in[idx];
    h4 o = {(_Float16)v.x, (_Float16)v.y, (_Float16)v.z, (_Float16)v.w};
    *(h4*)&out[idx] = o;
  }
}

// merged: blocks 0..127 transpose W1 (K=128), blocks 128..383 transpose W2 (K=256)
__global__ void k_cvt_wt2(const float* __restrict__ W1, _Float16* __restrict__ Wt1,
                          const float* __restrict__ W2, _Float16* __restrict__ Wt2) {
  int b = blockIdx.x, n = threadIdx.x;
  if (b < 128) Wt1[(size_t)n * 128 + b] = (_Float16)W1[(size_t)b * F + n];
  else {
    int k = b - 128;
    Wt2[(size_t)n * 256 + k] = (_Float16)W2[(size_t)k * F + n];
  }
}

// ---------------- CSR build ----------------

__global__ void k_hist(const int* __restrict__ dst, int Et, int* __restrict__ deg) {
  int i = blockIdx.x * blockDim.x + threadIdx.x;
  if (i < Et) atomicAdd(&deg[dst[i]], 1);
}

__global__ __launch_bounds__(1024) void k_scan1(const int* __restrict__ deg, int n,
                                                int* __restrict__ rowptr, int* __restrict__ bsum) {
  __shared__ int s[1024];
  int i = blockIdx.x * 1024 + threadIdx.x;
  int v = (i < n) ? deg[i] : 0;
  s[threadIdx.x] = v;
  __syncthreads();
  for (int off = 1; off < 1024; off <<= 1) {
    int add = (threadIdx.x >= off) ? s[threadIdx.x - off] : 0;
    __syncthreads();
    s[threadIdx.x] += add;
    __syncthreads();
  }
  if (i < n) rowptr[i] = s[threadIdx.x] - v;
  if (threadIdx.x == 1023) bsum[blockIdx.x] = s[1023];
}

__global__ void k_scan2(const int* __restrict__ bsum, int nb, int* __restrict__ boff) {
  int t = threadIdx.x;
  int v = (t < nb) ? bsum[t] : 0;
  int inc = v;
  for (int off = 1; off < 64; off <<= 1) {
    int y = __shfl_up(inc, off, 64);
    if (t >= off) inc += y;
  }
  boff[t] = inc - v;
}

// also produces the atomic work-copy rowwork (replaces fill[] + its memset)
__global__ void k_scan3(int n, int Et, int* __restrict__ rowptr,
                        int* __restrict__ rowwork, const int* __restrict__ boff) {
  int i = blockIdx.x * blockDim.x + threadIdx.x;
  if (i < n) {
    int v = rowptr[i] + boff[i >> 10];
    rowptr[i] = v;
    rowwork[i] = v;
  }
  if (i == 0) rowptr[n] = Et;
}

__global__ void k_fill(const int* __restrict__ src, const int* __restrict__ dst, int Et,
                       int* __restrict__ rowwork, int* __restrict__ csr_src) {
  int i = blockIdx.x * blockDim.x + threadIdx.x;
  if (i < Et) {
    int pos = atomicAdd(&rowwork[dst[i]], 1);
    csr_src[pos] = src[i];
  }
}

// ---------------- MFMA GEMM + fused attention-logit epilogue ----------------
// C[M,256] = A[M,K] @ B[K,256]; 64x256 tile per block, 4 waves.
// T14 pipeline: k+1 global loads issued after the first barrier, before MFMA.

__global__ __launch_bounds__(256) void k_gemm(const _Float16* __restrict__ A,
                                              const _Float16* __restrict__ Bt,
                                              _Float16* __restrict__ C,
                                              const float* __restrict__ a_src,
                                              const float* __restrict__ a_dst,
                                              float* __restrict__ als,
                                              float* __restrict__ ald,
                                              int M, int K) {
  __shared__ _Float16 As[64][40];    // +8 pad: 80B stride -> 2-way (free) frag reads
  __shared__ _Float16 Bs[256][40];
  int tid = threadIdx.x;
  int lane = tid & 63, w = tid >> 6;
  int rowBase = blockIdx.x * 64;
  f4 acc[4][4] = {};

  int arow = tid >> 2, akoff = (tid & 3) * 8;
  int arow_g = min(rowBase + arow, M - 1);
  const _Float16* Ap = A + (size_t)arow_g * K + akoff;
  const _Float16* Bp = Bt + (size_t)tid * K;   // thread t stages B-col t

  int kl = (lane >> 4) * 8;
  int rl = lane & 15;

  int nsteps = K >> 5;
  h8 av = *(const h8*)(Ap);
  h8 bv0 = *(const h8*)(Bp);
  h8 bv1 = *(const h8*)(Bp + 8);
  h8 bv2 = *(const h8*)(Bp + 16);
  h8 bv3 = *(const h8*)(Bp + 24);

  for (int s = 0; s < nsteps; ++s) {
    *(h8*)&As[arow][akoff] = av;
    *(h8*)&Bs[tid][0] = bv0;
    *(h8*)&Bs[tid][8] = bv1;
    *(h8*)&Bs[tid][16] = bv2;
    *(h8*)&Bs[tid][24] = bv3;
    __syncthreads();
    if (s + 1 < nsteps) {          // issue next-step loads early (hide under MFMA)
      int k0 = (s + 1) << 5;
      av = *(const h8*)(Ap + k0);
      bv0 = *(const h8*)(Bp + k0);
      bv1 = *(const h8*)(Bp + k0 + 8);
      bv2 = *(const h8*)(Bp + k0 + 16);
      bv3 = *(const h8*)(Bp + k0 + 24);
    }
    h8 af[4], bf[4];
#pragma unroll
    for (int fi = 0; fi < 4; ++fi) af[fi] = *(const h8*)&As[fi * 16 + rl][kl];
#pragma unroll
    for (int fj = 0; fj < 4; ++fj) bf[fj] = *(const h8*)&Bs[w * 64 + fj * 16 + rl][kl];
#pragma unroll
    for (int fi = 0; fi < 4; ++fi)
#pragma unroll
      for (int fj = 0; fj < 4; ++fj)
        acc[fi][fj] = __builtin_amdgcn_mfma_f32_16x16x32_f16(af[fi], bf[fj], acc[fi][fj], 0, 0, 0);
    __syncthreads();
  }

  int rquad = (lane >> 4) * 4;

#pragma unroll
  for (int fi = 0; fi < 4; ++fi)
#pragma unroll
    for (int fj = 0; fj < 4; ++fj) {
      int col = w * 64 + fj * 16 + rl;
#pragma unroll
      for (int r = 0; r < 4; ++r) {
        int row = rowBase + fi * 16 + rquad + r;
        if (row < M) C[(size_t)row * F + col] = (_Float16)acc[fi][fj][r];
      }
    }

  // fused al_s/al_d: wave w covers heads w*2 (fj 0,1) and w*2+1 (fj 2,3)
  int head0 = w * 2;
  float as0 = a_src[head0 * 32 + rl],      as1 = a_src[head0 * 32 + 16 + rl];
  float ad0 = a_dst[head0 * 32 + rl],      ad1 = a_dst[head0 * 32 + 16 + rl];
  float cs0 = a_src[head0 * 32 + 32 + rl], cs1 = a_src[head0 * 32 + 48 + rl];
  float cd0 = a_dst[head0 * 32 + 32 + rl], cd1 = a_dst[head0 * 32 + 48 + rl];
#pragma unroll
  for (int fi = 0; fi < 4; ++fi)
#pragma unroll
    for (int r = 0; r < 4; ++r) {
      float v0s = acc[fi][0][r] * as0 + acc[fi][1][r] * as1;
      float v0d = acc[fi][0][r] * ad0 + acc[fi][1][r] * ad1;
      float v1s = acc[fi][2][r] * cs0 + acc[fi][3][r] * cs1;
      float v1d = acc[fi][2][r] * cd0 + acc[fi][3][r] * cd1;
#pragma unroll
      for (int off = 8; off; off >>= 1) {
        v0s += __shfl_xor(v0s, off);
        v0d += __shfl_xor(v0d, off);
        v1s += __shfl_xor(v1s, off);
        v1d += __shfl_xor(v1d, off);
      }
      int row = rowBase + fi * 16 + rquad + r;
      if (rl == 0 && row < M) {
        als[row * HEADS + head0] = v0s;
        ald[row * HEADS + head0] = v0d;
        als[row * HEADS + head0 + 1] = v1s;
        ald[row * HEADS + head0 + 1] = v1d;
      }
    }
}

// ---------------- softmax -> alpha (fp16, gmem) ----------------
// wave per node; lanes: head hh = lane>>3, slot = lane&7.
// alpha[e][hh] = exp(leaky(al_s[src]+al_d[dst]) - m) / sum    (fp16)

__global__ __launch_bounds__(256) void k_alpha(const int* __restrict__ rowptr,
                                               const int* __restrict__ csr_src,
                                               const float* __restrict__ al_s,
                                               const float* __restrict__ al_d,
                                               _Float16* __restrict__ alpha,
                                               int n) {
  __shared__ float eps[4][64][8];
  int tid = threadIdx.x;
  int w = tid >> 6, lane = tid & 63;
  int node = blockIdx.x * 4 + w;
  if (node >= n) return;
  int base = rowptr[node];
  int d = rowptr[node + 1] - base;
  int hh = lane >> 3, slot = lane & 7;
  float alD = al_d[node * HEADS + hh];

  if (d <= 64) {
    float m = -1e30f;
    for (int j = slot; j < d; j += 8) {
      int s = csr_src[base + j];
      float e = al_s[s * HEADS + hh] + alD;
      e = (e > 0.f) ? e : 0.2f * e;
      eps[w][j][hh] = e;
      m = fmaxf(m, e);
    }
#pragma unroll
    for (int off = 4; off; off >>= 1) m = fmaxf(m, __shfl_xor(m, off));
    float sm = 0.f;
    for (int j = slot; j < d; j += 8) {
      float p = __expf(eps[w][j][hh] - m);
      eps[w][j][hh] = p;
      sm += p;
    }
#pragma unroll
    for (int off = 4; off; off >>= 1) sm += __shfl_xor(sm, off);
    float invs = 1.f / (sm + 1e-16f);
    for (int j = slot; j < d; j += 8)
      alpha[(size_t)(base + j) * 8 + hh] = (_Float16)(eps[w][j][hh] * invs);
  } else {
    float m = -1e30f;
    for (int j = slot; j < d; j += 8) {
      int s = csr_src[base + j];
      float e = al_s[s * HEADS + hh] + alD;
      e = (e > 0.f) ? e : 0.2f * e;
      m = fmaxf(m, e);
    }
#pragma unroll
    for (int off = 4; off; off >>= 1) m = fmaxf(m, __shfl_xor(m, off));
    float sm = 0.f;
    for (int j = slot; j < d; j += 8) {
      int s = csr_src[base + j];
      float e = al_s[s * HEADS + hh] + alD;
      e = (e > 0.f) ? e : 0.2f * e;
      sm += __expf(e - m);
    }
#pragma unroll
    for (int off = 4; off; off >>= 1) sm += __shfl_xor(sm, off);
    float invs = 1.f / (sm + 1e-16f);
    for (int j = slot; j < d; j += 8) {
      int s = csr_src[base + j];
      float e = al_s[s * HEADS + hh] + alD;
      e = (e > 0.f) ? e : 0.2f * e;
      alpha[(size_t)(base + j) * 8 + hh] = (_Float16)(__expf(e - m) * invs);
    }
  }
}

// ---------------- pure streaming gather (+bias, ELU) ----------------
// wave per node, no LDS, no barriers. Lane owns 4 channels (head hh = lane>>3).

template <bool F16OUT>
__global__ __launch_bounds__(256) void k_gather(const int* __restrict__ rowptr,
                                                const int* __restrict__ csr_src,
                                                const _Float16* __restrict__ alpha,
                                                const _Float16* __restrict__ h,
                                                const float* __restrict__ bias,
                                                float* __restrict__ outf,
                                                _Float16* __restrict__ outh,
                                                int n) {
  int tid = threadIdx.x;
  int w = tid >> 6, lane = tid & 63;
  int node = blockIdx.x * 4 + w;
  if (node >= n) return;
  int base = rowptr[node];
  int d = rowptr[node + 1] - base;
  int hh = lane >> 3;
  const _Float16* hc = h + (lane << 2);
  const _Float16* ap = alpha + hh;
  f4 acc = {0.f, 0.f, 0.f, 0.f};

  int j = 0;
  for (; j + 4 <= d; j += 4) {
    size_t e0 = base + j;
    int s0 = __builtin_amdgcn_readfirstlane(csr_src[e0]);
    int s1 = __builtin_amdgcn_readfirstlane(csr_src[e0 + 1]);
    int s2 = __builtin_amdgcn_readfirstlane(csr_src[e0 + 2]);
    int s3 = __builtin_amdgcn_readfirstlane(csr_src[e0 + 3]);
    float a0 = (float)ap[e0 * 8];
    float a1 = (float)ap[(e0 + 1) * 8];
    float a2 = (float)ap[(e0 + 2) * 8];
    float a3 = (float)ap[(e0 + 3) * 8];
    h4 v0 = *(const h4*)(hc + ((size_t)s0 << 8));
    h4 v1 = *(const h4*)(hc + ((size_t)s1 << 8));
    h4 v2 = *(const h4*)(hc + ((size_t)s2 << 8));
    h4 v3 = *(const h4*)(hc + ((size_t)s3 << 8));
    acc.x += a0 * (float)v0.x + a1 * (float)v1.x + a2 * (float)v2.x + a3 * (float)v3.x;
    acc.y += a0 * (float)v0.y + a1 * (float)v1.y + a2 * (float)v2.y + a3 * (float)v3.y;
    acc.z += a0 * (float)v0.z + a1 * (float)v1.z + a2 * (float)v2.z + a3 * (float)v3.z;
    acc.w += a0 * (float)v0.w + a1 * (float)v1.w + a2 * (float)v2.w + a3 * (float)v3.w;
  }
  for (; j < d; ++j) {
    size_t e0 = base + j;
    int s0 = __builtin_amdgcn_readfirstlane(csr_src[e0]);
    float a0 = (float)ap[e0 * 8];
    h4 v0 = *(const h4*)(hc + ((size_t)s0 << 8));
    acc.x += a0 * (float)v0.x;
    acc.y += a0 * (float)v0.y;
    acc.z += a0 * (float)v0.z;
    acc.w += a0 * (float)v0.w;
  }

  int c0 = lane << 2;
  float4 bv = *(const float4*)&bias[c0];
  float o0 = acc.x + bv.x;
  float o1 = acc.y + bv.y;
  float o2 = acc.z + bv.z;
  float o3 = acc.w + bv.w;
  o0 = (o0 > 0.f) ? o0 : expm1f(o0);
  o1 = (o1 > 0.f) ? o1 : expm1f(o1);
  o2 = (o2 > 0.f) ? o2 : expm1f(o2);
  o3 = (o3 > 0.f) ? o3 : expm1f(o3);
  if (F16OUT) {
    h4 o = {(_Float16)o0, (_Float16)o1, (_Float16)o2, (_Float16)o3};
    *(h4*)&outh[((size_t)node << 8) + c0] = o;
  } else {
    *(float4*)&outf[((size_t)node << 8) + c0] = make_float4(o0, o1, o2, o3);
  }
}

// ---------------- launch ----------------

extern "C" void kernel_launch(void* const* d_in, const int* in_sizes, int n_in,
                              void* d_out, int out_size, void* d_ws, size_t ws_size,
                              hipStream_t stream) {
  const float* x   = (const float*)d_in[0];
  const int*   ei  = (const int*)d_in[1];
  const float* W1  = (const float*)d_in[2];
  const float* a1s = (const float*)d_in[3];
  const float* a1d = (const float*)d_in[4];
  const float* b1  = (const float*)d_in[5];
  const float* W2  = (const float*)d_in[6];
  const float* a2s = (const float*)d_in[7];
  const float* a2d = (const float*)d_in[8];
  const float* b2  = (const float*)d_in[9];

  int n  = in_sizes[0] / 128;   // 50000
  int Et = in_sizes[1] / 2;     // 850000
  const int* srcp = ei;
  const int* dstp = ei + Et;

  char* ws = (char*)d_ws;
  auto alloc = [&](size_t bytes) {
    char* p = ws;
    ws += (bytes + 255) & ~(size_t)255;
    return p;
  };
  _Float16* xh      = (_Float16*)alloc((size_t)n * 128 * 2);
  _Float16* hbuf    = (_Float16*)alloc((size_t)n * F * 2);
  _Float16* Wt1     = (_Float16*)alloc((size_t)128 * F * 2);
  _Float16* Wt2     = (_Float16*)alloc((size_t)F * F * 2);
  _Float16* alpha   = (_Float16*)alloc((size_t)Et * HEADS * 2);  // 13.6 MB
  float*    als     = (float*)alloc((size_t)n * HEADS * 4);
  float*    ald     = (float*)alloc((size_t)n * HEADS * 4);
  int*      deg     = (int*)alloc((size_t)n * 4);
  int*      rowptr  = (int*)alloc((size_t)(n + 1) * 4);
  int*      rowwork = (int*)alloc((size_t)n * 4);
  int*      bsum    = (int*)alloc(64 * 4);
  int*      boff    = (int*)alloc(64 * 4);
  int*      csr     = (int*)alloc((size_t)Et * 4);
  _Float16* out1h   = (_Float16*)d_out;  // layer-1 fp16 staged in d_out
  float*    outF    = (float*)d_out;

  hipMemsetAsync(deg, 0, (size_t)n * 4, stream);

  k_cvt<<<(n * 128 / 4 + 255) / 256, 256, 0, stream>>>(x, xh, n * 128);
  k_cvt_wt2<<<384, 256, 0, stream>>>(W1, Wt1, W2, Wt2);

  int eb = (Et + 255) / 256;
  k_hist<<<eb, 256, 0, stream>>>(dstp, Et, deg);
  int nb = (n + 1023) / 1024;
  k_scan1<<<nb, 1024, 0, stream>>>(deg, n, rowptr, bsum);
  k_scan2<<<1, 64, 0, stream>>>(bsum, nb, boff);
  k_scan3<<<(n + 255) / 256, 256, 0, stream>>>(n, Et, rowptr, rowwork, boff);
  k_fill<<<eb, 256, 0, stream>>>(srcp, dstp, Et, rowwork, csr);

  int gb = (n + 63) / 64;
  int ab = (n + 3) / 4;
  // layer 1
  k_gemm<<<gb, 256, 0, stream>>>(xh, Wt1, hbuf, a1s, a1d, als, ald, n, 128);
  k_alpha<<<ab, 256, 0, stream>>>(rowptr, csr, als, ald, alpha, n);
  k_gather<true><<<ab, 256, 0, stream>>>(rowptr, csr, alpha, hbuf, b1, nullptr, out1h, n);
  // layer 2
  k_gemm<<<gb, 256, 0, stream>>>(out1h, Wt2, hbuf, a2s, a2d, als, ald, n, 256);
  k_alpha<<<ab, 256, 0, stream>>>(rowptr, csr, als, ald, alpha, n);
  k_gather<false><<<ab, 256, 0, stream>>>(rowptr, csr, alpha, hbuf, b2, outF, nullptr, n);
}

// Round 6
// 376.170 us; speedup vs baseline: 1.1204x; 1.1204x over previous
//
#include <hip/hip_runtime.h>
#include <hip/hip_bf16.h>

// GAT encoder, 2 layers, N=50000, Et=850000, IN=128, HID=OUT=256, HEADS=8, C=32.
// fp16 activations + MFMA f16 GEMM (128x256 tile, 8 waves, fused al epilogue);
// fused wave-per-node softmax+gather aggregation (round-4 k_agg structure).
// Dispatches: memset, prep(cvt+wt+hist), scan1, scan2, scan3, fill, [gemm, agg] x2.

#define HEADS 8
#define F 256

typedef _Float16 h8 __attribute__((ext_vector_type(8)));
typedef _Float16 h4 __attribute__((ext_vector_type(4)));
typedef float f4 __attribute__((ext_vector_type(4)));

#define WAVE_SYNC() do { __builtin_amdgcn_wave_barrier(); \
  asm volatile("s_waitcnt lgkmcnt(0)" ::: "memory"); \
  __builtin_amdgcn_wave_barrier(); } while (0)

// ---------------- prep: x->fp16 cvt | W1/W2 transpose->fp16 | dst histogram ----------------

__global__ void k_prep(const float* __restrict__ x, _Float16* __restrict__ xh, int n128,
                       const float* __restrict__ W1, _Float16* __restrict__ Wt1,
                       const float* __restrict__ W2, _Float16* __restrict__ Wt2,
                       const int* __restrict__ dst, int Et, int* __restrict__ deg,
                       int cvtB) {
  int b = blockIdx.x, tid = threadIdx.x;
  if (b < cvtB) {
    int idx = (b * 256 + tid) * 4;
    if (idx < n128) {
      float4 v = *(const float4*)&x[idx];
      h4 o = {(_Float16)v.x, (_Float16)v.y, (_Float16)v.z, (_Float16)v.w};
      *(h4*)&xh[idx] = o;
    }
  } else if (b < cvtB + 384) {
    int k = b - cvtB;
    if (k < 128) Wt1[(size_t)tid * 128 + k] = (_Float16)W1[(size_t)k * F + tid];
    else {
      k -= 128;
      Wt2[(size_t)tid * 256 + k] = (_Float16)W2[(size_t)k * F + tid];
    }
  } else {
    int i = (b - cvtB - 384) * 256 + tid;
    for (; i < Et; i += 512 * 256) atomicAdd(&deg[dst[i]], 1);
  }
}

// ---------------- CSR build ----------------

__global__ __launch_bounds__(1024) void k_scan1(const int* __restrict__ deg, int n,
                                                int* __restrict__ rowptr, int* __restrict__ bsum) {
  __shared__ int s[1024];
  int i = blockIdx.x * 1024 + threadIdx.x;
  int v = (i < n) ? deg[i] : 0;
  s[threadIdx.x] = v;
  __syncthreads();
  for (int off = 1; off < 1024; off <<= 1) {
    int add = (threadIdx.x >= off) ? s[threadIdx.x - off] : 0;
    __syncthreads();
    s[threadIdx.x] += add;
    __syncthreads();
  }
  if (i < n) rowptr[i] = s[threadIdx.x] - v;
  if (threadIdx.x == 1023) bsum[blockIdx.x] = s[1023];
}

__global__ void k_scan2(const int* __restrict__ bsum, int nb, int* __restrict__ boff) {
  int t = threadIdx.x;
  int v = (t < nb) ? bsum[t] : 0;
  int inc = v;
  for (int off = 1; off < 64; off <<= 1) {
    int y = __shfl_up(inc, off, 64);
    if (t >= off) inc += y;
  }
  boff[t] = inc - v;
}

__global__ void k_scan3(int n, int Et, int* __restrict__ rowptr,
                        int* __restrict__ rowwork, const int* __restrict__ boff) {
  int i = blockIdx.x * blockDim.x + threadIdx.x;
  if (i < n) {
    int v = rowptr[i] + boff[i >> 10];
    rowptr[i] = v;
    rowwork[i] = v;
  }
  if (i == 0) rowptr[n] = Et;
}

__global__ void k_fill(const int* __restrict__ src, const int* __restrict__ dst, int Et,
                       int* __restrict__ rowwork, int* __restrict__ csr_src) {
  int i = blockIdx.x * blockDim.x + threadIdx.x;
  if (i < Et) {
    int pos = atomicAdd(&rowwork[dst[i]], 1);
    csr_src[pos] = src[i];
  }
}

// ---------------- MFMA GEMM + fused attention-logit epilogue ----------------
// C[M,256] = A[M,K] @ B[K,256]; 128x256 tile per block, 512 threads / 8 waves.
// Wave w: rows (w&1)*64.., cols (w>>1)*64.. -> 4x4 fragments of 16x16x32.

__global__ __launch_bounds__(512) void k_gemm(const _Float16* __restrict__ A,
                                              const _Float16* __restrict__ Bt,
                                              _Float16* __restrict__ C,
                                              const float* __restrict__ a_src,
                                              const float* __restrict__ a_dst,
                                              float* __restrict__ als,
                                              float* __restrict__ ald,
                                              int M, int K) {
  __shared__ _Float16 As[128][40];   // +8 pad
  __shared__ _Float16 Bs[256][40];
  int tid = threadIdx.x;
  int lane = tid & 63, w = tid >> 6;
  int wr = w & 1, wc = w >> 1;
  int rowBase = blockIdx.x * 128;
  f4 acc[4][4] = {};

  int arow = tid >> 2, akoff = (tid & 3) * 8;
  int arow_g = min(rowBase + arow, M - 1);
  const _Float16* Ap = A + (size_t)arow_g * K + akoff;
  int bc = tid >> 1, bkoff = (tid & 1) * 16;
  const _Float16* Bp = Bt + (size_t)bc * K + bkoff;

  int kl = (lane >> 4) * 8;
  int rl = lane & 15;

  int nsteps = K >> 5;
  h8 av = *(const h8*)(Ap);
  h8 bv0 = *(const h8*)(Bp);
  h8 bv1 = *(const h8*)(Bp + 8);

  for (int s = 0; s < nsteps; ++s) {
    *(h8*)&As[arow][akoff] = av;
    *(h8*)&Bs[bc][bkoff] = bv0;
    *(h8*)&Bs[bc][bkoff + 8] = bv1;
    __syncthreads();
    if (s + 1 < nsteps) {          // T14: issue next-step loads under MFMA
      int k0 = (s + 1) << 5;
      av = *(const h8*)(Ap + k0);
      bv0 = *(const h8*)(Bp + k0);
      bv1 = *(const h8*)(Bp + k0 + 8);
    }
    h8 af[4], bf[4];
#pragma unroll
    for (int fi = 0; fi < 4; ++fi) af[fi] = *(const h8*)&As[wr * 64 + fi * 16 + rl][kl];
#pragma unroll
    for (int fj = 0; fj < 4; ++fj) bf[fj] = *(const h8*)&Bs[wc * 64 + fj * 16 + rl][kl];
#pragma unroll
    for (int fi = 0; fi < 4; ++fi)
#pragma unroll
      for (int fj = 0; fj < 4; ++fj)
        acc[fi][fj] = __builtin_amdgcn_mfma_f32_16x16x32_f16(af[fi], bf[fj], acc[fi][fj], 0, 0, 0);
    __syncthreads();
  }

  int rquad = (lane >> 4) * 4;

#pragma unroll
  for (int fi = 0; fi < 4; ++fi)
#pragma unroll
    for (int fj = 0; fj < 4; ++fj) {
      int col = wc * 64 + fj * 16 + rl;
#pragma unroll
      for (int r = 0; r < 4; ++r) {
        int row = rowBase + wr * 64 + fi * 16 + rquad + r;
        if (row < M) C[(size_t)row * F + col] = (_Float16)acc[fi][fj][r];
      }
    }

  // fused al_s/al_d: wave covers heads wc*2 (fj 0,1) and wc*2+1 (fj 2,3)
  int head0 = wc * 2;
  float as0 = a_src[head0 * 32 + rl],      as1 = a_src[head0 * 32 + 16 + rl];
  float ad0 = a_dst[head0 * 32 + rl],      ad1 = a_dst[head0 * 32 + 16 + rl];
  float cs0 = a_src[head0 * 32 + 32 + rl], cs1 = a_src[head0 * 32 + 48 + rl];
  float cd0 = a_dst[head0 * 32 + 32 + rl], cd1 = a_dst[head0 * 32 + 48 + rl];
#pragma unroll
  for (int fi = 0; fi < 4; ++fi)
#pragma unroll
    for (int r = 0; r < 4; ++r) {
      float v0s = acc[fi][0][r] * as0 + acc[fi][1][r] * as1;
      float v0d = acc[fi][0][r] * ad0 + acc[fi][1][r] * ad1;
      float v1s = acc[fi][2][r] * cs0 + acc[fi][3][r] * cs1;
      float v1d = acc[fi][2][r] * cd0 + acc[fi][3][r] * cd1;
#pragma unroll
      for (int off = 8; off; off >>= 1) {
        v0s += __shfl_xor(v0s, off);
        v0d += __shfl_xor(v0d, off);
        v1s += __shfl_xor(v1s, off);
        v1d += __shfl_xor(v1d, off);
      }
      int row = rowBase + wr * 64 + fi * 16 + rquad + r;
      if (rl == 0 && row < M) {
        als[row * HEADS + head0] = v0s;
        ald[row * HEADS + head0] = v0d;
        als[row * HEADS + head0 + 1] = v1s;
        ald[row * HEADS + head0 + 1] = v1d;
      }
    }
}

// ---------------- wave-per-node softmax + gather aggregate (+bias, ELU) ----------------
// 256 threads = 4 waves = 4 nodes. Lanes: softmax hh = lane>>3, slot = lane&7;
// gather: lane owns channels lane*4..lane*4+3 (head = lane>>3, consistent).

template <bool F16OUT>
__global__ __launch_bounds__(256) void k_agg(const int* __restrict__ rowptr,
                                             const int* __restrict__ csr_src,
                                             const float* __restrict__ al_s,
                                             const float* __restrict__ al_d,
                                             const _Float16* __restrict__ h,
                                             const float* __restrict__ bias,
                                             float* __restrict__ outf,
                                             _Float16* __restrict__ outh,
                                             int n) {
  __shared__ float eps[4][64][8];
  __shared__ int ssrc[4][64];
  int tid = threadIdx.x;
  int w = tid >> 6, lane = tid & 63;
  int node = blockIdx.x * 4 + w;
  if (node >= n) return;
  int base = rowptr[node];
  int d = rowptr[node + 1] - base;
  int hh = lane >> 3, slot = lane & 7;
  float alD = al_d[node * HEADS + hh];

  float invs;
  f4 facc = {0.f, 0.f, 0.f, 0.f};
  const _Float16* hc = h + (lane << 2);

  if (d <= 64) {
    float m = -1e30f;
    for (int j = slot; j < d; j += 8) {
      int s = csr_src[base + j];
      if (hh == 0) ssrc[w][j] = s;
      float e = al_s[s * HEADS + hh] + alD;
      e = (e > 0.f) ? e : 0.2f * e;
      eps[w][j][hh] = e;
      m = fmaxf(m, e);
    }
#pragma unroll
    for (int off = 4; off; off >>= 1) m = fmaxf(m, __shfl_xor(m, off));
    float sm = 0.f;
    for (int j = slot; j < d; j += 8) {
      float p = __expf(eps[w][j][hh] - m);
      eps[w][j][hh] = p;
      sm += p;
    }
#pragma unroll
    for (int off = 4; off; off >>= 1) sm += __shfl_xor(sm, off);
    invs = 1.f / (sm + 1e-16f);
    WAVE_SYNC();
    int j = 0;
    for (; j + 4 <= d; j += 4) {
      int s0 = __builtin_amdgcn_readfirstlane(ssrc[w][j]);
      int s1 = __builtin_amdgcn_readfirstlane(ssrc[w][j + 1]);
      int s2 = __builtin_amdgcn_readfirstlane(ssrc[w][j + 2]);
      int s3 = __builtin_amdgcn_readfirstlane(ssrc[w][j + 3]);
      float p0 = eps[w][j][hh], p1 = eps[w][j + 1][hh];
      float p2 = eps[w][j + 2][hh], p3 = eps[w][j + 3][hh];
      h4 v0 = *(const h4*)(hc + ((size_t)s0 << 8));
      h4 v1 = *(const h4*)(hc + ((size_t)s1 << 8));
      h4 v2 = *(const h4*)(hc + ((size_t)s2 << 8));
      h4 v3 = *(const h4*)(hc + ((size_t)s3 << 8));
      facc.x += p0 * (float)v0.x + p1 * (float)v1.x + p2 * (float)v2.x + p3 * (float)v3.x;
      facc.y += p0 * (float)v0.y + p1 * (float)v1.y + p2 * (float)v2.y + p3 * (float)v3.y;
      facc.z += p0 * (float)v0.z + p1 * (float)v1.z + p2 * (float)v2.z + p3 * (float)v3.z;
      facc.w += p0 * (float)v0.w + p1 * (float)v1.w + p2 * (float)v2.w + p3 * (float)v3.w;
    }
    for (; j < d; ++j) {
      int s0 = __builtin_amdgcn_readfirstlane(ssrc[w][j]);
      float p0 = eps[w][j][hh];
      h4 v0 = *(const h4*)(hc + ((size_t)s0 << 8));
      facc.x += p0 * (float)v0.x;
      facc.y += p0 * (float)v0.y;
      facc.z += p0 * (float)v0.z;
      facc.w += p0 * (float)v0.w;
    }
  } else {
    // general path (rare): 2 streaming passes + chunked stage/gather
    float m = -1e30f;
    for (int j = slot; j < d; j += 8) {
      int s = csr_src[base + j];
      float e = al_s[s * HEADS + hh] + alD;
      e = (e > 0.f) ? e : 0.2f * e;
      m = fmaxf(m, e);
    }
#pragma unroll
    for (int off = 4; off; off >>= 1) m = fmaxf(m, __shfl_xor(m, off));
    float sm = 0.f;
    for (int j = slot; j < d; j += 8) {
      int s = csr_src[base + j];
      float e = al_s[s * HEADS + hh] + alD;
      e = (e > 0.f) ? e : 0.2f * e;
      sm += __expf(e - m);
    }
#pragma unroll
    for (int off = 4; off; off >>= 1) sm += __shfl_xor(sm, off);
    invs = 1.f / (sm + 1e-16f);
    for (int c0 = 0; c0 < d; c0 += 64) {
      int cn = min(64, d - c0);
      WAVE_SYNC();
      for (int j = slot; j < cn; j += 8) {
        int s = csr_src[base + c0 + j];
        if (hh == 0) ssrc[w][j] = s;
        float e = al_s[s * HEADS + hh] + alD;
        e = (e > 0.f) ? e : 0.2f * e;
        eps[w][j][hh] = __expf(e - m);
      }
      WAVE_SYNC();
      for (int j = 0; j < cn; ++j) {
        int s0 = __builtin_amdgcn_readfirstlane(ssrc[w][j]);
        float p0 = eps[w][j][hh];
        h4 v0 = *(const h4*)(hc + ((size_t)s0 << 8));
        facc.x += p0 * (float)v0.x;
        facc.y += p0 * (float)v0.y;
        facc.z += p0 * (float)v0.z;
        facc.w += p0 * (float)v0.w;
      }
    }
  }

  int c0 = lane << 2;
  float4 bv = *(const float4*)&bias[c0];
  float o0 = facc.x * invs + bv.x;
  float o1 = facc.y * invs + bv.y;
  float o2 = facc.z * invs + bv.z;
  float o3 = facc.w * invs + bv.w;
  o0 = (o0 > 0.f) ? o0 : expm1f(o0);
  o1 = (o1 > 0.f) ? o1 : expm1f(o1);
  o2 = (o2 > 0.f) ? o2 : expm1f(o2);
  o3 = (o3 > 0.f) ? o3 : expm1f(o3);
  if (F16OUT) {
    h4 o = {(_Float16)o0, (_Float16)o1, (_Float16)o2, (_Float16)o3};
    *(h4*)&outh[((size_t)node << 8) + c0] = o;
  } else {
    *(float4*)&outf[((size_t)node << 8) + c0] = make_float4(o0, o1, o2, o3);
  }
}

// ---------------- launch ----------------

extern "C" void kernel_launch(void* const* d_in, const int* in_sizes, int n_in,
                              void* d_out, int out_size, void* d_ws, size_t ws_size,
                              hipStream_t stream) {
  const float* x   = (const float*)d_in[0];
  const int*   ei  = (const int*)d_in[1];
  const float* W1  = (const float*)d_in[2];
  const float* a1s = (const float*)d_in[3];
  const float* a1d = (const float*)d_in[4];
  const float* b1  = (const float*)d_in[5];
  const float* W2  = (const float*)d_in[6];
  const float* a2s = (const float*)d_in[7];
  const float* a2d = (const float*)d_in[8];
  const float* b2  = (const float*)d_in[9];

  int n  = in_sizes[0] / 128;   // 50000
  int Et = in_sizes[1] / 2;     // 850000
  const int* srcp = ei;
  const int* dstp = ei + Et;

  char* ws = (char*)d_ws;
  auto alloc = [&](size_t bytes) {
    char* p = ws;
    ws += (bytes + 255) & ~(size_t)255;
    return p;
  };
  _Float16* xh      = (_Float16*)alloc((size_t)n * 128 * 2);
  _Float16* hbuf    = (_Float16*)alloc((size_t)n * F * 2);
  _Float16* Wt1     = (_Float16*)alloc((size_t)128 * F * 2);
  _Float16* Wt2     = (_Float16*)alloc((size_t)F * F * 2);
  float*    als     = (float*)alloc((size_t)n * HEADS * 4);
  float*    ald     = (float*)alloc((size_t)n * HEADS * 4);
  int*      deg     = (int*)alloc((size_t)n * 4);
  int*      rowptr  = (int*)alloc((size_t)(n + 1) * 4);
  int*      rowwork = (int*)alloc((size_t)n * 4);
  int*      bsum    = (int*)alloc(64 * 4);
  int*      boff    = (int*)alloc(64 * 4);
  int*      csr     = (int*)alloc((size_t)Et * 4);
  _Float16* out1h   = (_Float16*)d_out;  // layer-1 fp16 staged in d_out
  float*    outF    = (float*)d_out;

  hipMemsetAsync(deg, 0, (size_t)n * 4, stream);

  int n128 = n * 128;
  int cvtB = (n128 / 4 + 255) / 256;
  k_prep<<<cvtB + 384 + 512, 256, 0, stream>>>(x, xh, n128, W1, Wt1, W2, Wt2,
                                               dstp, Et, deg, cvtB);

  int nb = (n + 1023) / 1024;
  k_scan1<<<nb, 1024, 0, stream>>>(deg, n, rowptr, bsum);
  k_scan2<<<1, 64, 0, stream>>>(bsum, nb, boff);
  k_scan3<<<(n + 255) / 256, 256, 0, stream>>>(n, Et, rowptr, rowwork, boff);
  k_fill<<<(Et + 255) / 256, 256, 0, stream>>>(srcp, dstp, Et, rowwork, csr);

  int gb = (n + 127) / 128;
  int ab = (n + 3) / 4;
  // layer 1
  k_gemm<<<gb, 512, 0, stream>>>(xh, Wt1, hbuf, a1s, a1d, als, ald, n, 128);
  k_agg<true><<<ab, 256, 0, stream>>>(rowptr, csr, als, ald, hbuf, b1, nullptr, out1h, n);
  // layer 2
  k_gemm<<<gb, 512, 0, stream>>>(out1h, Wt2, hbuf, a2s, a2d, als, ald, n, 256);
  k_agg<false><<<ab, 256, 0, stream>>>(rowptr, csr, als, ald, hbuf, b2, outF, nullptr, n);
}

// Round 7
// 348.340 us; speedup vs baseline: 1.2099x; 1.0799x over previous
//
#include <hip/hip_runtime.h>
#include <hip/hip_bf16.h>

// GAT encoder, 2 layers, N=50000, Et=850000, IN=128, HID=OUT=256, HEADS=8, C=32.
// fp16 activations + MFMA f16 GEMM (128x256 tile; layer-1 converts f32 A in staging
// and carries CSR-fill blocks); single-pass no-max softmax+gather aggregation.
// Dispatches: memset, prep(wt+hist), scan1, scan23, gemm1+fill, agg1, gemm2, agg2.

#define HEADS 8
#define F 256

typedef _Float16 h8 __attribute__((ext_vector_type(8)));
typedef _Float16 h4 __attribute__((ext_vector_type(4)));
typedef float f4 __attribute__((ext_vector_type(4)));

// ---------------- prep: W1/W2 transpose->fp16 | dst histogram ----------------

__global__ void k_prep(const float* __restrict__ W1, _Float16* __restrict__ Wt1,
                       const float* __restrict__ W2, _Float16* __restrict__ Wt2,
                       const int* __restrict__ dst, int Et, int* __restrict__ deg) {
  int b = blockIdx.x, tid = threadIdx.x;
  if (b < 128) {
    Wt1[(size_t)tid * 128 + b] = (_Float16)W1[(size_t)b * F + tid];
  } else if (b < 384) {
    int k = b - 128;
    Wt2[(size_t)tid * 256 + k] = (_Float16)W2[(size_t)k * F + tid];
  } else {
    int i = (b - 384) * 256 + tid;
    for (; i < Et; i += 512 * 256) atomicAdd(&deg[dst[i]], 1);
  }
}

// ---------------- CSR build (4-aligned segments) ----------------

__global__ __launch_bounds__(1024) void k_scan1(const int* __restrict__ deg, int n,
                                                int* __restrict__ rowptr, int* __restrict__ bsum) {
  __shared__ int s[1024];
  int i = blockIdx.x * 1024 + threadIdx.x;
  int v = (i < n) ? ((deg[i] + 3) & ~3) : 0;   // ceil4 so every segment starts 16B-aligned
  s[threadIdx.x] = v;
  __syncthreads();
  for (int off = 1; off < 1024; off <<= 1) {
    int add = (threadIdx.x >= off) ? s[threadIdx.x - off] : 0;
    __syncthreads();
    s[threadIdx.x] += add;
    __syncthreads();
  }
  if (i < n) rowptr[i] = s[threadIdx.x] - v;
  if (threadIdx.x == 1023) bsum[blockIdx.x] = s[1023];
}

// merged scan2+scan3: each block reduces its bsum prefix (<=64 entries) itself
__global__ void k_scan23(int n, const int* __restrict__ bsum,
                         int* __restrict__ rowptr, int* __restrict__ rowwork) {
  __shared__ int boffs;
  int nbx = blockIdx.x >> 2;   // which scan1-block this 256-chunk belongs to
  if (threadIdx.x < 64) {
    int t = threadIdx.x;
    int v = (t < nbx) ? bsum[t] : 0;
#pragma unroll
    for (int off = 32; off; off >>= 1) v += __shfl_xor(v, off, 64);
    if (t == 0) boffs = v;
  }
  __syncthreads();
  int i = blockIdx.x * 256 + threadIdx.x;
  if (i < n) {
    int v = rowptr[i] + boffs;
    rowptr[i] = v;
    rowwork[i] = v;
  }
}

// ---------------- MFMA GEMM + fused al epilogue (+ optional CSR-fill blocks) ----------------
// C[M,256] = A[M,K] @ B[K,256]; 128x256 tile, 512 threads / 8 waves.
// AF32: A is f32, converted to fp16 during LDS staging (layer 1).
// FILL: blocks >= gemmBlocks run the CSR scatter-fill instead (overlaps with MFMA work).

template <bool AF32, bool FILL>
__global__ __launch_bounds__(512) void k_gemm(const void* __restrict__ Av,
                                              const _Float16* __restrict__ Bt,
                                              _Float16* __restrict__ C,
                                              const float* __restrict__ a_src,
                                              const float* __restrict__ a_dst,
                                              float* __restrict__ als,
                                              float* __restrict__ ald,
                                              int M, int K,
                                              const int* __restrict__ esrc,
                                              const int* __restrict__ edst,
                                              int Et, int* __restrict__ rowwork,
                                              int* __restrict__ csr, int gemmBlocks) {
  if (FILL && (int)blockIdx.x >= gemmBlocks) {
    int i = ((int)blockIdx.x - gemmBlocks) * 512 + threadIdx.x;
    int stride = ((int)gridDim.x - gemmBlocks) * 512;
    for (; i < Et; i += stride) {
      int pos = atomicAdd(&rowwork[edst[i]], 1);
      csr[pos] = esrc[i];
    }
    return;
  }

  __shared__ _Float16 As[128][40];   // +8 pad
  __shared__ _Float16 Bs[256][40];
  int tid = threadIdx.x;
  int lane = tid & 63, w = tid >> 6;
  int wr = w & 1, wc = w >> 1;
  int rowBase = blockIdx.x * 128;
  f4 acc[4][4] = {};

  int arow = tid >> 2, akoff = (tid & 3) * 8;
  int arow_g = min(rowBase + arow, M - 1);
  const _Float16* Ap = (const _Float16*)Av + (size_t)arow_g * K + akoff;
  const float*    Apf = (const float*)Av + (size_t)arow_g * K + akoff;
  int bc = tid >> 1, bkoff = (tid & 1) * 16;
  const _Float16* Bp = Bt + (size_t)bc * K + bkoff;

  int kl = (lane >> 4) * 8;
  int rl = lane & 15;

  int nsteps = K >> 5;
  h8 av;
  float4 af0, af1;
  if (AF32) { af0 = *(const float4*)(Apf); af1 = *(const float4*)(Apf + 4); }
  else av = *(const h8*)(Ap);
  h8 bv0 = *(const h8*)(Bp);
  h8 bv1 = *(const h8*)(Bp + 8);

  for (int s = 0; s < nsteps; ++s) {
    if (AF32) {
      h8 t = {(_Float16)af0.x, (_Float16)af0.y, (_Float16)af0.z, (_Float16)af0.w,
              (_Float16)af1.x, (_Float16)af1.y, (_Float16)af1.z, (_Float16)af1.w};
      *(h8*)&As[arow][akoff] = t;
    } else {
      *(h8*)&As[arow][akoff] = av;
    }
    *(h8*)&Bs[bc][bkoff] = bv0;
    *(h8*)&Bs[bc][bkoff + 8] = bv1;
    __syncthreads();
    if (s + 1 < nsteps) {          // T14: issue next-step loads under MFMA
      int k0 = (s + 1) << 5;
      if (AF32) { af0 = *(const float4*)(Apf + k0); af1 = *(const float4*)(Apf + k0 + 4); }
      else av = *(const h8*)(Ap + k0);
      bv0 = *(const h8*)(Bp + k0);
      bv1 = *(const h8*)(Bp + k0 + 8);
    }
    h8 afr[4], bfr[4];
#pragma unroll
    for (int fi = 0; fi < 4; ++fi) afr[fi] = *(const h8*)&As[wr * 64 + fi * 16 + rl][kl];
#pragma unroll
    for (int fj = 0; fj < 4; ++fj) bfr[fj] = *(const h8*)&Bs[wc * 64 + fj * 16 + rl][kl];
#pragma unroll
    for (int fi = 0; fi < 4; ++fi)
#pragma unroll
      for (int fj = 0; fj < 4; ++fj)
        acc[fi][fj] = __builtin_amdgcn_mfma_f32_16x16x32_f16(afr[fi], bfr[fj], acc[fi][fj], 0, 0, 0);
    __syncthreads();
  }

  int rquad = (lane >> 4) * 4;

#pragma unroll
  for (int fi = 0; fi < 4; ++fi)
#pragma unroll
    for (int fj = 0; fj < 4; ++fj) {
      int col = wc * 64 + fj * 16 + rl;
#pragma unroll
      for (int r = 0; r < 4; ++r) {
        int row = rowBase + wr * 64 + fi * 16 + rquad + r;
        if (row < M) C[(size_t)row * F + col] = (_Float16)acc[fi][fj][r];
      }
    }

  // fused al_s/al_d: wave covers heads wc*2 (fj 0,1) and wc*2+1 (fj 2,3)
  int head0 = wc * 2;
  float as0 = a_src[head0 * 32 + rl],      as1 = a_src[head0 * 32 + 16 + rl];
  float ad0 = a_dst[head0 * 32 + rl],      ad1 = a_dst[head0 * 32 + 16 + rl];
  float cs0 = a_src[head0 * 32 + 32 + rl], cs1 = a_src[head0 * 32 + 48 + rl];
  float cd0 = a_dst[head0 * 32 + 32 + rl], cd1 = a_dst[head0 * 32 + 48 + rl];
#pragma unroll
  for (int fi = 0; fi < 4; ++fi)
#pragma unroll
    for (int r = 0; r < 4; ++r) {
      float v0s = acc[fi][0][r] * as0 + acc[fi][1][r] * as1;
      float v0d = acc[fi][0][r] * ad0 + acc[fi][1][r] * ad1;
      float v1s = acc[fi][2][r] * cs0 + acc[fi][3][r] * cs1;
      float v1d = acc[fi][2][r] * cd0 + acc[fi][3][r] * cd1;
#pragma unroll
      for (int off = 8; off; off >>= 1) {
        v0s += __shfl_xor(v0s, off);
        v0d += __shfl_xor(v0d, off);
        v1s += __shfl_xor(v1s, off);
        v1d += __shfl_xor(v1d, off);
      }
      int row = rowBase + wr * 64 + fi * 16 + rquad + r;
      if (rl == 0 && row < M) {
        als[row * HEADS + head0] = v0s;
        ald[row * HEADS + head0] = v0d;
        als[row * HEADS + head0 + 1] = v1s;
        ald[row * HEADS + head0 + 1] = v1d;
      }
    }
}

// ---------------- single-pass softmax+gather aggregate (+bias, ELU) ----------------
// Softmax shift-invariance: skip segment-max (logits bounded, exp safe in f32).
// Wave per node; lane owns 4 channels, head hh = lane>>3. No LDS, no syncs.

template <bool F16OUT>
__global__ __launch_bounds__(256) void k_agg(const int* __restrict__ rowptr,
                                             const int* __restrict__ deg,
                                             const int* __restrict__ csr,
                                             const float* __restrict__ al_s,
                                             const float* __restrict__ al_d,
                                             const _Float16* __restrict__ h,
                                             const float* __restrict__ bias,
                                             float* __restrict__ outf,
                                             _Float16* __restrict__ outh,
                                             int n) {
  int tid = threadIdx.x;
  int w = tid >> 6, lane = tid & 63;
  int node = blockIdx.x * 4 + w;
  if (node >= n) return;
  int base = rowptr[node];          // 16B-aligned segment
  int d = deg[node];
  int hh = lane >> 3;
  float alD = al_d[node * HEADS + hh];
  const _Float16* hc = h + (lane << 2);
  const int* cp = csr + base;

  f4 acc = {0.f, 0.f, 0.f, 0.f};
  float sp = 0.f;
  int j = 0;
  if (d >= 4) {
    int4 sv = *(const int4*)cp;     // same-addr across lanes -> broadcast
    for (; j + 4 <= d; j += 4) {
      int4 svn = sv;
      if (j + 8 <= d) svn = *(const int4*)(cp + j + 4);   // prefetch next quad
      float e0 = al_s[sv.x * HEADS + hh] + alD;
      float e1 = al_s[sv.y * HEADS + hh] + alD;
      float e2 = al_s[sv.z * HEADS + hh] + alD;
      float e3 = al_s[sv.w * HEADS + hh] + alD;
      e0 = (e0 > 0.f) ? e0 : 0.2f * e0;
      e1 = (e1 > 0.f) ? e1 : 0.2f * e1;
      e2 = (e2 > 0.f) ? e2 : 0.2f * e2;
      e3 = (e3 > 0.f) ? e3 : 0.2f * e3;
      float p0 = __expf(e0), p1 = __expf(e1), p2 = __expf(e2), p3 = __expf(e3);
      h4 v0 = *(const h4*)(hc + ((size_t)sv.x << 8));
      h4 v1 = *(const h4*)(hc + ((size_t)sv.y << 8));
      h4 v2 = *(const h4*)(hc + ((size_t)sv.z << 8));
      h4 v3 = *(const h4*)(hc + ((size_t)sv.w << 8));
      acc.x += p0 * (float)v0.x + p1 * (float)v1.x + p2 * (float)v2.x + p3 * (float)v3.x;
      acc.y += p0 * (float)v0.y + p1 * (float)v1.y + p2 * (float)v2.y + p3 * (float)v3.y;
      acc.z += p0 * (float)v0.z + p1 * (float)v1.z + p2 * (float)v2.z + p3 * (float)v3.z;
      acc.w += p0 * (float)v0.w + p1 * (float)v1.w + p2 * (float)v2.w + p3 * (float)v3.w;
      sp += p0 + p1 + p2 + p3;
      sv = svn;
    }
  }
  for (; j < d; ++j) {
    int s = cp[j];
    float e = al_s[s * HEADS + hh] + alD;
    e = (e > 0.f) ? e : 0.2f * e;
    float p = __expf(e);
    h4 v = *(const h4*)(hc + ((size_t)s << 8));
    acc.x += p * (float)v.x;
    acc.y += p * (float)v.y;
    acc.z += p * (float)v.z;
    acc.w += p * (float)v.w;
    sp += p;
  }

  float invs = 1.f / (sp + 1e-16f);
  int c0 = lane << 2;
  float4 bv = *(const float4*)&bias[c0];
  float o0 = acc.x * invs + bv.x;
  float o1 = acc.y * invs + bv.y;
  float o2 = acc.z * invs + bv.z;
  float o3 = acc.w * invs + bv.w;
  o0 = (o0 > 0.f) ? o0 : expm1f(o0);
  o1 = (o1 > 0.f) ? o1 : expm1f(o1);
  o2 = (o2 > 0.f) ? o2 : expm1f(o2);
  o3 = (o3 > 0.f) ? o3 : expm1f(o3);
  if (F16OUT) {
    h4 o = {(_Float16)o0, (_Float16)o1, (_Float16)o2, (_Float16)o3};
    *(h4*)&outh[((size_t)node << 8) + c0] = o;
  } else {
    *(float4*)&outf[((size_t)node << 8) + c0] = make_float4(o0, o1, o2, o3);
  }
}

// ---------------- launch ----------------

extern "C" void kernel_launch(void* const* d_in, const int* in_sizes, int n_in,
                              void* d_out, int out_size, void* d_ws, size_t ws_size,
                              hipStream_t stream) {
  const float* x   = (const float*)d_in[0];
  const int*   ei  = (const int*)d_in[1];
  const float* W1  = (const float*)d_in[2];
  const float* a1s = (const float*)d_in[3];
  const float* a1d = (const float*)d_in[4];
  const float* b1  = (const float*)d_in[5];
  const float* W2  = (const float*)d_in[6];
  const float* a2s = (const float*)d_in[7];
  const float* a2d = (const float*)d_in[8];
  const float* b2  = (const float*)d_in[9];

  int n  = in_sizes[0] / 128;   // 50000
  int Et = in_sizes[1] / 2;     // 850000
  const int* srcp = ei;
  const int* dstp = ei + Et;

  char* ws = (char*)d_ws;
  auto alloc = [&](size_t bytes) {
    char* p = ws;
    ws += (bytes + 255) & ~(size_t)255;
    return p;
  };
  _Float16* hbuf    = (_Float16*)alloc((size_t)n * F * 2);
  _Float16* Wt1     = (_Float16*)alloc((size_t)128 * F * 2);
  _Float16* Wt2     = (_Float16*)alloc((size_t)F * F * 2);
  float*    als     = (float*)alloc((size_t)n * HEADS * 4);
  float*    ald     = (float*)alloc((size_t)n * HEADS * 4);
  int*      deg     = (int*)alloc((size_t)n * 4);
  int*      rowptr  = (int*)alloc((size_t)(n + 1) * 4);
  int*      rowwork = (int*)alloc((size_t)n * 4);
  int*      bsum    = (int*)alloc(64 * 4);
  int*      csr     = (int*)alloc(((size_t)Et + 4 * (size_t)n) * 4);  // ceil4 segments
  _Float16* out1h   = (_Float16*)d_out;  // layer-1 fp16 staged in d_out
  float*    outF    = (float*)d_out;

  hipMemsetAsync(deg, 0, (size_t)n * 4, stream);

  k_prep<<<384 + 512, 256, 0, stream>>>(W1, Wt1, W2, Wt2, dstp, Et, deg);

  int nb = (n + 1023) / 1024;
  k_scan1<<<nb, 1024, 0, stream>>>(deg, n, rowptr, bsum);
  k_scan23<<<(n + 255) / 256, 256, 0, stream>>>(n, bsum, rowptr, rowwork);

  int gb = (n + 127) / 128;
  int ab = (n + 3) / 4;
  // layer 1: gemm (f32 A, converts in staging) + CSR fill riding along
  k_gemm<true, true><<<gb + 1024, 512, 0, stream>>>(x, Wt1, hbuf, a1s, a1d, als, ald,
                                                    n, 128, srcp, dstp, Et, rowwork, csr, gb);
  k_agg<true><<<ab, 256, 0, stream>>>(rowptr, deg, csr, als, ald, hbuf, b1, nullptr, out1h, n);
  // layer 2
  k_gemm<false, false><<<gb, 512, 0, stream>>>(out1h, Wt2, hbuf, a2s, a2d, als, ald,
                                               n, 256, nullptr, nullptr, 0, nullptr, nullptr, gb);
  k_agg<false><<<ab, 256, 0, stream>>>(rowptr, deg, csr, als, ald, hbuf, b2, outF, nullptr, n);
}